// Round 5
// baseline (835.118 us; speedup 1.0000x reference)
//
#include <hip/hip_runtime.h>
#include <hip/hip_bf16.h>

typedef __bf16 bf16x8 __attribute__((ext_vector_type(8)));
typedef float  f32x4  __attribute__((ext_vector_type(4)));

#define B_   16
#define CIN  64
#define COUT 64
#define H_   256
#define W_   256
#define TY   16
#define SLOT (258 * 64)

// ---------------- Kernel 1: modulate + demodulate weights -> bf16 [b][tap][co][ci]
__global__ void modw_kernel(const float* __restrict__ weight,
                            const float* __restrict__ y,
                            __bf16* __restrict__ w1g) {
  const int co = blockIdx.x;
  const int b  = blockIdx.y;
  const int ci = threadIdx.x;               // 64 threads = 1 wave
  const float c  = 0.041666666666666664f;   // (64*9)^-0.5 = 1/24
  const float yv = y[b*CIN + ci] * c;
  float w[9];
  float s = 0.0f;
#pragma unroll
  for (int t = 0; t < 9; ++t) {
    float wv = weight[(co*CIN + ci)*9 + t] * yv;
    w[t] = wv;
    s += wv * wv;
  }
#pragma unroll
  for (int off = 32; off > 0; off >>= 1) s += __shfl_xor(s, off, 64);
  const float d = rsqrtf(s + 1e-8f);
#pragma unroll
  for (int t = 0; t < 9; ++t)
    w1g[((b*9 + t)*COUT + co)*CIN + ci] = (__bf16)(w[t] * d);
}

// ---------------- staging helpers: one thread = 8 ci (group cg) x 4 px
__device__ __forceinline__ void stage_load(const float* __restrict__ X,
                                           int b, int yy, int tid, float4* f) {
  const int cg = tid >> 6;
  const int px_base = 4 * (tid & 63);
  const float* xrow = X + ((long)b * (CIN * H_ * W_) + (long)yy * W_);
#pragma unroll
  for (int j = 0; j < 8; ++j)
    f[j] = *reinterpret_cast<const float4*>(xrow + (long)(cg * 8 + j) * (H_ * W_) + px_base);
}

__device__ __forceinline__ void stage_write(__bf16* __restrict__ xs, int slot,
                                            int tid, const float4* f, bool valid) {
  const int cg = tid >> 6;
  const int px_base = 4 * (tid & 63);
  bf16x8 frag[4];
  if (valid) {
#pragma unroll
    for (int j = 0; j < 8; ++j) {
      frag[0][j] = (__bf16)f[j].x;
      frag[1][j] = (__bf16)f[j].y;
      frag[2][j] = (__bf16)f[j].z;
      frag[3][j] = (__bf16)f[j].w;
    }
  } else {
#pragma unroll
    for (int o = 0; o < 4; ++o)
#pragma unroll
      for (int j = 0; j < 8; ++j) frag[o][j] = (__bf16)0.f;
  }
#pragma unroll
  for (int oo = 0; oo < 4; ++oo) {
    const int o  = (oo + tid) & 3;            // rotate to spread write banks
    const int pl = px_base + o + 1;           // px_lds (cols 0 / 257 are zero pads)
    const int gs = cg ^ (pl & 7);             // XOR bank swizzle
    *reinterpret_cast<bf16x8*>(&xs[slot * SLOT + pl * 64 + gs * 8]) = frag[o];
  }
}

// ---------------- Kernel 2: strip-mined implicit-GEMM conv, 2 output rows/iter.
// One block per (b, 16-row strip), 8 iterations of 2 rows. Rolling 4-slot LDS
// row buffer (129 KB). Each x-fragment ds_read from input row r feeds BOTH
// output rows (as different taps) -> LDS read traffic x0.67 per output
// (was the measured 80%-of-iteration bottleneck at ~204 B/cyc/CU).
__global__ __launch_bounds__(512, 2)
void conv_kernel(const float* __restrict__ X,
                 const __bf16* __restrict__ w1g,
                 float* __restrict__ out) {
  const int y0   = blockIdx.x * TY;
  const int b    = blockIdx.y;
  const int tid  = threadIdx.x;
  const int lane = tid & 63;
  const int wv   = tid >> 6;        // wave 0..7
  const int cgw  = wv & 1;          // co half (32 co)
  const int pg   = wv >> 1;         // px quarter (64 px)
  const int q    = lane >> 4;       // 0..3
  const int n    = lane & 15;       // 0..15

  __shared__ __bf16 xs[4 * SLOT];   // 129 KB: 4 row slots [258][64] bf16, swizzled

  // zero the pad columns (px_lds = 0 and 257) of all 4 slots, once
  {
    const int s = tid >> 7, r = tid & 127;
    const int col = (r < 64) ? 0 : 257;
    xs[s * SLOT + col * 64 + (r & 63)] = (__bf16)0.f;
  }

  // hoisted weight fragments: B-operand, col = co = n, k = ci = q*8+j (+32 for ks=1)
  bf16x8 wfr[2][9][2];
#pragma unroll
  for (int c2 = 0; c2 < 2; ++c2) {
    const int co = cgw * 32 + c2 * 16 + n;
#pragma unroll
    for (int tap = 0; tap < 9; ++tap) {
      const __bf16* wp = w1g + ((b * 9 + tap) * COUT + co) * CIN + q * 8;
      wfr[c2][tap][0] = *reinterpret_cast<const bf16x8*>(wp);        // ci = q*8+j
      wfr[c2][tap][1] = *reinterpret_cast<const bf16x8*>(wp + 32);   // ci = 32+q*8+j
    }
  }

  // prologue: stage rows y0-1 .. y0+2 into slot (row+4)&3
  {
    float4 f[8];
#pragma unroll
    for (int k = 0; k < 4; ++k) {
      const int yy = y0 - 1 + k;
      const bool valid = (yy >= 0);             // yy <= y0+2 <= 242 < H_
      if (valid) stage_load(X, b, yy, tid, f);
      stage_write(xs, (yy + 4) & 3, tid, f, valid);
    }
  }

  float4 pfA[8], pfB[8];            // prefetch registers for rows y+3, y+4
  for (int t2 = 0; t2 < TY / 2; ++t2) {
    const int y = y0 + 2 * t2;
    __syncthreads();                               // S1: staged rows visible

    const bool do_pf = (t2 < TY / 2 - 1);          // last iter: no prefetch
    const int yA = y + 3, yB = y + 4;
    const bool okA = do_pf && (yA < H_);
    const bool okB = do_pf && (yB < H_);
    if (okA) stage_load(X, b, yA, tid, pfA);       // issue loads; land during MFMA
    if (okB) stage_load(X, b, yB, tid, pfB);

    f32x4 acc[2][2][4];                            // [orow][c2][nt]
#pragma unroll
    for (int o = 0; o < 2; ++o)
#pragma unroll
      for (int c2 = 0; c2 < 2; ++c2)
#pragma unroll
        for (int nt = 0; nt < 4; ++nt) acc[o][c2][nt] = (f32x4){0.f, 0.f, 0.f, 0.f};

#pragma unroll
    for (int rr = 0; rr < 4; ++rr) {               // input row y-1+rr
      const __bf16* sl = &xs[((y - 1 + rr + 4) & 3) * SLOT];
      // out row y   uses rr=0..2 as dy=rr   -> tapA = rr*3+dx
      // out row y+1 uses rr=1..3 as dy=rr-1 -> tapB = (rr-1)*3+dx
#pragma unroll
      for (int dx = 0; dx < 3; ++dx) {
        const int p3 = (n + dx) & 7;               // px&7 (pg*64, nt*16 = 0 mod 8)
        const int o0 = (q ^ p3) * 8;
        const int o1 = ((q + 4) ^ p3) * 8;
#pragma unroll
        for (int nt = 0; nt < 4; ++nt) {
          const int px = pg * 64 + nt * 16 + n + dx;
          const bf16x8 a0 = *reinterpret_cast<const bf16x8*>(&sl[px * 64 + o0]);
          const bf16x8 a1 = *reinterpret_cast<const bf16x8*>(&sl[px * 64 + o1]);
          if (rr <= 2) {
            const int tapA = rr * 3 + dx;
            acc[0][0][nt] = __builtin_amdgcn_mfma_f32_16x16x32_bf16(a0, wfr[0][tapA][0], acc[0][0][nt], 0, 0, 0);
            acc[0][0][nt] = __builtin_amdgcn_mfma_f32_16x16x32_bf16(a1, wfr[0][tapA][1], acc[0][0][nt], 0, 0, 0);
            acc[0][1][nt] = __builtin_amdgcn_mfma_f32_16x16x32_bf16(a0, wfr[1][tapA][0], acc[0][1][nt], 0, 0, 0);
            acc[0][1][nt] = __builtin_amdgcn_mfma_f32_16x16x32_bf16(a1, wfr[1][tapA][1], acc[0][1][nt], 0, 0, 0);
          }
          if (rr >= 1) {
            const int tapB = (rr - 1) * 3 + dx;
            acc[1][0][nt] = __builtin_amdgcn_mfma_f32_16x16x32_bf16(a0, wfr[0][tapB][0], acc[1][0][nt], 0, 0, 0);
            acc[1][0][nt] = __builtin_amdgcn_mfma_f32_16x16x32_bf16(a1, wfr[0][tapB][1], acc[1][0][nt], 0, 0, 0);
            acc[1][1][nt] = __builtin_amdgcn_mfma_f32_16x16x32_bf16(a0, wfr[1][tapB][0], acc[1][1][nt], 0, 0, 0);
            acc[1][1][nt] = __builtin_amdgcn_mfma_f32_16x16x32_bf16(a1, wfr[1][tapB][1], acc[1][1][nt], 0, 0, 0);
          }
        }
      }
    }
    __syncthreads();                               // S2: frees slots (y-1),(y); pf landed

    // epilogue: D[row=px][col=co]: lane (q,n) holds px = q*4+r at co-offset n
#pragma unroll
    for (int o = 0; o < 2; ++o) {
#pragma unroll
      for (int c2 = 0; c2 < 2; ++c2) {
        const int co = cgw * 32 + c2 * 16 + n;
#pragma unroll
        for (int nt = 0; nt < 4; ++nt) {
          const int px0 = pg * 64 + nt * 16 + q * 4;
          *reinterpret_cast<float4*>(out + ((long)(b * COUT + co) * H_ + (y + o)) * W_ + px0) =
              *reinterpret_cast<const float4*>(&acc[o][c2][nt]);
        }
      }
    }

    // write prefetched rows y+3 -> slot (y+3)&3, y+4 -> slot (y+4)&3
    // (slots freed by S2: rows y-1 and y; next iter needs y+1..y+4)
    if (do_pf) {
      stage_write(xs, (yA + 4) & 3, tid, pfA, okA);
      stage_write(xs, (yB + 4) & 3, tid, pfB, okB);
    }
  }
}

extern "C" void kernel_launch(void* const* d_in, const int* in_sizes, int n_in,
                              void* d_out, int out_size, void* d_ws, size_t ws_size,
                              hipStream_t stream) {
  const float* X = (const float*)d_in[0];   // (16, 64, 256, 256) fp32
  const float* y = (const float*)d_in[1];   // (16, 64) fp32
  const float* w = (const float*)d_in[2];   // (64, 64, 3, 3) fp32
  float* outp = (float*)d_out;              // (16, 64, 256, 256) fp32
  __bf16* w1g = (__bf16*)d_ws;              // 16*9*64*64 bf16 = 1.13 MB scratch

  modw_kernel<<<dim3(COUT, B_), 64, 0, stream>>>(w, y, w1g);
  conv_kernel<<<dim3(H_ / TY, B_), 512, 0, stream>>>(X, w1g, outp);
}

// Round 7
// 812.478 us; speedup vs baseline: 1.0279x; 1.0279x over previous
//
#include <hip/hip_runtime.h>
#include <hip/hip_bf16.h>

typedef __bf16 bf16x8 __attribute__((ext_vector_type(8)));
typedef float  f32x4  __attribute__((ext_vector_type(4)));

#define B_   16
#define CIN  64
#define COUT 64
#define H_   256
#define W_   256
#define TY   16
#define PXB  128            // px per block (half row)
#define SW   144            // staged px per slot: [x0-8, x0+136)
#define SLOT3 (SW * 64)     // 9216 bf16 = 18432 B per slot

// ---------------- Kernel 1: modulate + demodulate weights -> bf16 [b][tap][co][ci]
// 4 waves per block (one co each) for better CU utilization.
__global__ void modw_kernel(const float* __restrict__ weight,
                            const float* __restrict__ y,
                            __bf16* __restrict__ w1g) {
  const int co = blockIdx.x * 4 + threadIdx.y;
  const int b  = blockIdx.y;
  const int ci = threadIdx.x;               // 64 threads = 1 wave
  const float c  = 0.041666666666666664f;   // (64*9)^-0.5 = 1/24
  const float yv = y[b*CIN + ci] * c;
  float w[9];
  float s = 0.0f;
#pragma unroll
  for (int t = 0; t < 9; ++t) {
    float wv = weight[(co*CIN + ci)*9 + t] * yv;
    w[t] = wv;
    s += wv * wv;
  }
#pragma unroll
  for (int off = 32; off > 0; off >>= 1) s += __shfl_xor(s, off, 64);
  const float d = rsqrtf(s + 1e-8f);
#pragma unroll
  for (int t = 0; t < 9; ++t)
    w1g[((b*9 + t)*COUT + co)*CIN + ci] = (__bf16)(w[t] * d);
}

// ---------------- staging: one row -> one LDS slot (144 px x 64 ci, swizzled)
// main: 256 thr = 8 ci-groups x 32 px-quads, covers staged-local px [8,136)
// halo: 128 thr = 16 px x 8 ci-groups, covers staged-local [0,8) u [136,144)
__device__ __forceinline__ void stage_row(const float* __restrict__ X,
                                          __bf16* __restrict__ xs, int slot,
                                          int b, int yy, int x0, int tid) {
  const bool rowok = (yy >= 0) && (yy < H_);
  const float* xrow = X + ((long)b * (CIN * H_ * W_) + (long)(rowok ? yy : 0) * W_);
  __bf16* sl = xs + slot * SLOT3;

  // ---- main 128 px ----
  {
    const int cg   = tid >> 5;          // ci group 0..7
    const int pgid = tid & 31;          // px quad 0..31
    const int gpx  = x0 + 4 * pgid;     // global px (always 0..255)
    float4 f[8];
    if (rowok) {
#pragma unroll
      for (int j = 0; j < 8; ++j)
        f[j] = *reinterpret_cast<const float4*>(xrow + (long)(cg * 8 + j) * (H_ * W_) + gpx);
    }
    bf16x8 frag[4];
#pragma unroll
    for (int o = 0; o < 4; ++o)
#pragma unroll
      for (int j = 0; j < 8; ++j)
        frag[o][j] = rowok ? (__bf16)((&f[j].x)[o]) : (__bf16)0.f;
#pragma unroll
    for (int oo = 0; oo < 4; ++oo) {
      const int o  = (oo + tid) & 3;        // rotate to spread write banks
      const int pl = 8 + 4 * pgid + o;      // staged-local px
      const int gs = cg ^ (pl & 7);         // XOR bank swizzle
      *reinterpret_cast<bf16x8*>(&sl[pl * 64 + gs * 8]) = frag[o];
    }
  }

  // ---- halo 16 px ----
  if (tid < 128) {
    const int i  = tid >> 3;                // 0..15
    const int cg = tid & 7;                 // ci group
    const int pl = (i < 8) ? i : (128 + i); // staged-local: 0..7 or 136..143
    const int gpx = x0 - 8 + pl;
    const bool ok = rowok && (gpx >= 0) && (gpx < W_);
    bf16x8 v;
#pragma unroll
    for (int j = 0; j < 8; ++j)
      v[j] = ok ? (__bf16)xrow[(long)(cg * 8 + j) * (H_ * W_) + gpx] : (__bf16)0.f;
    const int gs = cg ^ (pl & 7);
    *reinterpret_cast<bf16x8*>(&sl[pl * 64 + gs * 8]) = v;
  }
}

// ---------------- Kernel 2: strip-mined implicit-GEMM conv, px-half blocks.
// Block = (px-half, 16-row strip, b): 256 thr / 4 waves, 55 KB LDS ->
// TWO blocks co-resident per CU. While one block sits in its barrier/drain,
// the sibling computes (m114 TLP) - attacks the measured stall mass directly.
// 4 waves = 2 co-halves x 2 px-quarters; per wave 2 co-tiles x 4 px-tiles.
__global__ __launch_bounds__(256)
void conv_kernel(const float* __restrict__ X,
                 const __bf16* __restrict__ w1g,
                 float* __restrict__ out) {
  const int x0   = blockIdx.x * PXB;
  const int y0   = blockIdx.y * TY;
  const int b    = blockIdx.z;
  const int tid  = threadIdx.x;
  const int lane = tid & 63;
  const int wv   = tid >> 6;        // wave 0..3
  const int cgw  = wv & 1;          // co half (32 co)
  const int pg   = wv >> 1;         // px quarter (64 px of this half)
  const int q    = lane >> 4;       // 0..3
  const int n    = lane & 15;       // 0..15

  __shared__ __bf16 xs[3 * SLOT3];  // 55 KB: 3 row slots [144][64] bf16, swizzled

  // prologue: stage rows y0-1, y0, y0+1 into slot (yy+1)%3
  for (int k = 0; k < 3; ++k) {
    const int yy = y0 - 1 + k;
    stage_row(X, xs, (yy + 1) % 3, b, yy, x0, tid);
  }

  for (int ty = 0; ty < TY; ++ty) {
    const int y = y0 + ty;
    __syncthreads();                               // S1: staged rows visible

    f32x4 acc[2][4];
#pragma unroll
    for (int c2 = 0; c2 < 2; ++c2)
#pragma unroll
      for (int nt = 0; nt < 4; ++nt) acc[c2][nt] = (f32x4){0.f, 0.f, 0.f, 0.f};

    __builtin_amdgcn_s_setprio(1);
#pragma unroll
    for (int dy = 0; dy < 3; ++dy) {
      const __bf16* sl = &xs[((y + dy) % 3) * SLOT3];   // row y-1+dy -> slot (y+dy)%3

      // weight fragments for this dy (L2-resident, reused across 4 nt)
      bf16x8 wfr[2][3][2];
#pragma unroll
      for (int c2 = 0; c2 < 2; ++c2) {
        const int co = cgw * 32 + c2 * 16 + n;
#pragma unroll
        for (int dx = 0; dx < 3; ++dx) {
          const __bf16* wp = w1g + ((b * 9 + dy * 3 + dx) * COUT + co) * CIN + q * 8;
          wfr[c2][dx][0] = *reinterpret_cast<const bf16x8*>(wp);
          wfr[c2][dx][1] = *reinterpret_cast<const bf16x8*>(wp + 32);
        }
      }

#pragma unroll
      for (int dx = 0; dx < 3; ++dx) {
        const int p3 = (n + dx + 7) & 7;           // pl&7 (pg*64, nt*16 = 0 mod 8)
        const int o0 = (q ^ p3) * 8;
        const int o1 = ((q + 4) ^ p3) * 8;
#pragma unroll
        for (int nt = 0; nt < 4; ++nt) {
          const int pl = pg * 64 + nt * 16 + n + dx + 7;   // px + (dx-1) + 8
          const bf16x8 a0 = *reinterpret_cast<const bf16x8*>(&sl[pl * 64 + o0]);
          const bf16x8 a1 = *reinterpret_cast<const bf16x8*>(&sl[pl * 64 + o1]);
          acc[0][nt] = __builtin_amdgcn_mfma_f32_16x16x32_bf16(a0, wfr[0][dx][0], acc[0][nt], 0, 0, 0);
          acc[0][nt] = __builtin_amdgcn_mfma_f32_16x16x32_bf16(a1, wfr[0][dx][1], acc[0][nt], 0, 0, 0);
          acc[1][nt] = __builtin_amdgcn_mfma_f32_16x16x32_bf16(a0, wfr[1][dx][0], acc[1][nt], 0, 0, 0);
          acc[1][nt] = __builtin_amdgcn_mfma_f32_16x16x32_bf16(a1, wfr[1][dx][1], acc[1][nt], 0, 0, 0);
        }
      }
    }
    __builtin_amdgcn_s_setprio(0);
    __syncthreads();                               // S2: frees slot (y)%3 (row y-1)

    // epilogue: D[row=px][col=co]: lane (q,n) holds 4 consecutive px at co-offset n
#pragma unroll
    for (int c2 = 0; c2 < 2; ++c2) {
      const int co = cgw * 32 + c2 * 16 + n;
#pragma unroll
      for (int nt = 0; nt < 4; ++nt) {
        const int px0 = x0 + pg * 64 + nt * 16 + q * 4;
        *reinterpret_cast<float4*>(out + ((long)(b * COUT + co) * H_ + y) * W_ + px0) =
            *reinterpret_cast<const float4*>(&acc[c2][nt]);
      }
    }

    // restage row y+2 into the slot freed by S2; sibling block's compute
    // hides this block's load latency (no reg-prefetch -> no spill risk)
    if (ty < TY - 1)
      stage_row(X, xs, (y + 3) % 3, b, y + 2, x0, tid);
  }
}

extern "C" void kernel_launch(void* const* d_in, const int* in_sizes, int n_in,
                              void* d_out, int out_size, void* d_ws, size_t ws_size,
                              hipStream_t stream) {
  const float* X = (const float*)d_in[0];   // (16, 64, 256, 256) fp32
  const float* y = (const float*)d_in[1];   // (16, 64) fp32
  const float* w = (const float*)d_in[2];   // (64, 64, 3, 3) fp32
  float* outp = (float*)d_out;              // (16, 64, 256, 256) fp32
  __bf16* w1g = (__bf16*)d_ws;              // 16*9*64*64 bf16 = 1.13 MB scratch

  modw_kernel<<<dim3(COUT / 4, B_), dim3(64, 4), 0, stream>>>(w, y, w1g);
  conv_kernel<<<dim3(W_ / PXB, H_ / TY, B_), 256, 0, stream>>>(X, w1g, outp);
}